// Round 4
// baseline (26.528 us; speedup 1.0000x reference)
//
#include <hip/hip_runtime.h>

namespace {
constexpr int Bc  = 16;
constexpr int Nc  = 96;
constexpr int KRc = 16;
constexpr int KAc = 8;
constexpr int NOUT = KRc + KAc;        // 24
constexpr int NNb  = Nc - 1;           // 95 neighbors per atom
constexpr float RCRf = 5.2f;
constexpr float RCAf = 3.5f;
constexpr float L2E  = 1.4426950408889634f;
}

typedef float v2f __attribute__((ext_vector_type(2)));

__device__ __forceinline__ v2f sp(float x) { return (v2f){x, x}; }
__device__ __forceinline__ v2f pfma(v2f a, v2f b, v2f c) {
    return __builtin_elementwise_fma(a, b, c);
}
__device__ __forceinline__ v2f pmax(v2f a, v2f b) {
    return __builtin_elementwise_max(a, b);
}
__device__ __forceinline__ v2f pexp2(v2f x) {
    return (v2f){__builtin_amdgcn_exp2f(x.x), __builtin_amdgcn_exp2f(x.y)};
}
__device__ __forceinline__ v2f pcosr(v2f rev) {   // cos(2*pi*rev), rev >= 0
    return (v2f){__builtin_amdgcn_cosf(__builtin_amdgcn_fractf(rev.x)),
                 __builtin_amdgcn_cosf(__builtin_amdgcn_fractf(rev.y))};
}
__device__ __forceinline__ v2f psqrt(v2f x) {
    return (v2f){__builtin_amdgcn_sqrtf(x.x), __builtin_amdgcn_sqrtf(x.y)};
}
__device__ __forceinline__ float cos_rev(float rev) {
    return __builtin_amdgcn_cosf(__builtin_amdgcn_fractf(rev));
}

// 384 threads = 4 groups x 96. Thread owns column j = t%96 (j==95 dead),
// group h = t/96 owns rounds rr in [1+12h, 13+12h) (rr==48 masked).
// Pairs: (j, (j+rr) mod 95) — exact single cover of all C(95,2) pairs.
__global__ __launch_bounds__(384) void ani_feat_kernel(
    const float* __restrict__ coords,      // (B,N,3)
    const int*   __restrict__ atom_types,  // (N,)
    const float* __restrict__ EtaR,        // (T,KR)
    const float* __restrict__ ShfR,        // (T,KR)
    const float* __restrict__ Zeta,        // (T,KA)
    const float* __restrict__ EtaA,        // (T,KA)
    float* __restrict__ out)               // (B,N,24)
{
    const int bi = blockIdx.x;             // b*N + i
    const int b  = bi / Nc;
    const int i  = bi - b * Nc;
    const int t  = threadIdx.x;

    __shared__ float ux[96], uy[96], uz[96], ud[96], ufa[96], sfr[96];
    __shared__ v2f  pux[96], puy[96], puz[96], pud[96], pufa[96];
    __shared__ float pr[24][KRc];
    __shared__ float red[6][KAc];

    const int ti = atom_types[i];

    // ---- phase 1: scalar per-neighbor staging (slot 95 mirrors slot 0) ----
    if (t < 96) {
        const float* cb = coords + (size_t)(b * Nc) * 3;
        int s = (t == 95) ? 0 : t;
        int j = s + (s >= i);
        float dx = cb[i*3+0] - cb[j*3+0];
        float dy = cb[i*3+1] - cb[j*3+1];
        float dz = cb[i*3+2] - cb[j*3+2];
        float d2 = dx*dx + dy*dy + dz*dz;
        float d  = __builtin_amdgcn_sqrtf(d2);
        float inv = 1.0f / d;
        ux[t] = dx*inv; uy[t] = dy*inv; uz[t] = dz*inv; ud[t] = d;
        ufa[t] = fmaf(cos_rev(d * (0.5f / RCAf)), 0.5f, 0.5f);
        sfr[t] = (t == 95) ? 0.0f
                           : fmaf(cos_rev(d * (0.5f / RCRf)), 0.5f, 0.5f);
    }
    __syncthreads();

    // ---- phase 2: pair-shifted packed SoA (one aligned b64 per operand) ----
    if (t < 96) {
        int s0 = (t == 95) ? 0 : t;
        int s1 = s0 + 1; if (s1 >= NNb) s1 = 0;
        pux[t]  = (v2f){ux[s0],  ux[s1]};
        puy[t]  = (v2f){uy[s0],  uy[s1]};
        puz[t]  = (v2f){uz[s0],  uz[s1]};
        pud[t]  = (v2f){ud[s0],  ud[s1]};
        pufa[t] = (v2f){ufa[s0], ufa[s1]};
    }

    // ---- radial G2 (all 384 threads): k per lane-of-16, 24 groups ----
    {
        const int k = t & 15, g = t >> 4;
        float er  = EtaR[ti * KRc + k];
        float sr  = ShfR[ti * KRc + k];
        float erL = -er * L2E;
        float acc = 0.0f;
        for (int jj = g; jj < NNb; jj += 24) {
            float dd = ud[jj] - sr;
            acc += __builtin_amdgcn_exp2f(erL * dd * dd) * sfr[jj];
        }
        pr[g][k] = acc;
    }

    // ---- angular parameters + uniform fast-path detection ----
    float zek[KAc], c1k[KAc], eaL[KAc];
#pragma unroll
    for (int k = 0; k < KAc; ++k) {
        float z = Zeta[ti * KAc + k];
        zek[k] = z;
        c1k[k] = 1.0f - z;
        eaL[k] = EtaA[ti * KAc + k] * L2E;
    }
    bool zuni = true;
#pragma unroll
    for (int k = 1; k < KAc; ++k) zuni = zuni && (zek[k] == zek[0]);
    const float dL = eaL[1] - eaL[0];
    bool arith = true;
#pragma unroll
    for (int k = 2; k < KAc; ++k)
        arith = arith && (fabsf(eaL[k] - (eaL[0] + dL * (float)k)) <=
                          1e-5f * fabsf(eaL[k]) + 1e-7f);
    const bool fast = zuni && arith && (zek[0] == 32.0f);
    const float ea0 = eaL[0], c10 = c1k[0];

    __syncthreads();

    // ---- per-thread angular setup ----
    const int h = t / 96;                   // 0..3
    const int j = t - 96 * h;               // 0..95 (95 dead)
    const float Ax = ux[j], Ay = uy[j], Az = uz[j], Aw = ud[j];
    const float faj  = (j < NNb) ? ufa[j] : 0.0f;
    const float d2A  = Aw * Aw;
    const float m2Aw = -2.0f * Aw;
    const int   rrb  = 1 + 12 * h;
    int j2 = j + rrb; if (j2 >= NNb) j2 -= NNb;
    const float live1 = (h < 3) ? 1.0f : 0.0f;   // h==3 has 11 rounds, not 12

    float av[KAc];

    if (fast) {
        v2f acc2[KAc];
#pragma unroll
        for (int k = 0; k < KAc; ++k) acc2[k] = sp(0.0f);

        const v2f fajv = sp(faj);
        const v2f fajl = (v2f){faj, faj * live1};

#define ANG_BODY(FAJV)                                                       \
        {                                                                    \
            v2f Bx = pux[j2], By = puy[j2], Bz = puz[j2];                    \
            v2f Bw = pud[j2], fb = pufa[j2];                                 \
            v2f cosv = pfma(sp(Ax), Bx, pfma(sp(Ay), By, sp(Az) * Bz));      \
            v2f sAB  = pfma(Bw, Bw, sp(d2A));                                \
            v2f d23sq = pmax(pfma(sp(m2Aw) * Bw, cosv, sAB), sp(0.0f));      \
            v2f f23 = pfma(pcosr(psqrt(d23sq) * sp(0.5f / RCAf)),            \
                           sp(0.5f), sp(0.5f));                              \
            v2f fprod = (FAJV) * fb * f23;                                   \
            v2f s  = sAB + d23sq;                                            \
            v2f tt = pmax(sp(1.0f) + cosv, sp(0.0f));                        \
            v2f t2 = tt*tt, t4 = t2*t2, t8 = t4*t4, t16 = t8*t8;             \
            v2f F = t16 * t16 * fprod;                                       \
            v2f e = pexp2(pfma(sp(-ea0), s, sp(c10)));                       \
            v2f q = pexp2(sp(-dL) * s);                                      \
            acc2[0] = pfma(F, e, acc2[0]);                                   \
            e = e * q; acc2[1] = pfma(F, e, acc2[1]);                        \
            e = e * q; acc2[2] = pfma(F, e, acc2[2]);                        \
            e = e * q; acc2[3] = pfma(F, e, acc2[3]);                        \
            e = e * q; acc2[4] = pfma(F, e, acc2[4]);                        \
            e = e * q; acc2[5] = pfma(F, e, acc2[5]);                        \
            e = e * q; acc2[6] = pfma(F, e, acc2[6]);                        \
            e = e * q; acc2[7] = pfma(F, e, acc2[7]);                        \
            j2 += 2; if (j2 >= NNb) j2 -= NNb;                               \
        }

        ANG_BODY(fajv)   // rr = rrb+0, rrb+1
        ANG_BODY(fajv)   // rr = rrb+2, rrb+3
        ANG_BODY(fajv)   // rr = rrb+4, rrb+5
        ANG_BODY(fajv)   // rr = rrb+6, rrb+7
        ANG_BODY(fajv)   // rr = rrb+8, rrb+9
        ANG_BODY(fajl)   // rr = rrb+10, rrb+11 (rr==48 masked for h==3)
#undef ANG_BODY

#pragma unroll
        for (int k = 0; k < KAc; ++k) av[k] = acc2[k].x + acc2[k].y;
    } else {
        // generic fallback: scalar per-pair, arbitrary Zeta/EtaA
        float accS[KAc];
#pragma unroll
        for (int k = 0; k < KAc; ++k) accS[k] = 0.0f;
        int jj2 = j2;
        for (int rr = rrb; rr < rrb + 12; ++rr) {
            float lv = (rr <= 47) ? 1.0f : 0.0f;
            float Bx = ux[jj2], By = uy[jj2], Bz = uz[jj2];
            float Bw = ud[jj2], fb = ufa[jj2];
            float cosv = fmaf(Ax, Bx, fmaf(Ay, By, Az * Bz));
            float sAB  = fmaf(Bw, Bw, d2A);
            float d23sq = fmaxf(fmaf(m2Aw * Bw, cosv, sAB), 0.0f);
            float d23 = __builtin_amdgcn_sqrtf(d23sq);
            float f23 = fmaf(cos_rev(d23 * (0.5f / RCAf)), 0.5f, 0.5f);
            float fprod = faj * fb * f23 * lv;
            float s  = sAB + d23sq;
            float tt = fmaxf(1.0f + cosv, 0.0f);
            float l2 = __builtin_amdgcn_logf(tt);   // log2; -inf at 0 is fine
#pragma unroll
            for (int k = 0; k < KAc; ++k) {
                float E = fmaf(zek[k], l2, c1k[k]);
                E = fmaf(-eaL[k], s, E);
                accS[k] += __builtin_amdgcn_exp2f(E) * fprod;
            }
            ++jj2; if (jj2 >= NNb) jj2 = 0;
        }
#pragma unroll
        for (int k = 0; k < KAc; ++k) av[k] = accS[k];
    }

    // ---- reductions ----
    const int lane = t & 63, wv = t >> 6;
#pragma unroll
    for (int k = 0; k < KAc; ++k) {
        float v = av[k];
#pragma unroll
        for (int off = 32; off; off >>= 1) v += __shfl_xor(v, off, 64);
        if (lane == 0) red[wv][k] = v;
    }
    __syncthreads();

    if (t < KAc) {
        float v = 0.0f;
#pragma unroll
        for (int w = 0; w < 6; ++w) v += red[w][t];
        out[bi * NOUT + KRc + t] = v;
    }
    if (t < KRc) {
        float s = 0.0f;
#pragma unroll
        for (int g = 0; g < 24; ++g) s += pr[g][t];
        out[bi * NOUT + t] = s;
    }
}

extern "C" void kernel_launch(void* const* d_in, const int* in_sizes, int n_in,
                              void* d_out, int out_size, void* d_ws, size_t ws_size,
                              hipStream_t stream) {
    const float* coords     = (const float*)d_in[0];
    const int*   atom_types = (const int*)d_in[1];
    const float* EtaR       = (const float*)d_in[2];
    const float* ShfR       = (const float*)d_in[3];
    const float* Zeta       = (const float*)d_in[4];
    const float* EtaA       = (const float*)d_in[5];
    float* out = (float*)d_out;

    ani_feat_kernel<<<dim3(Bc * Nc), dim3(384), 0, stream>>>(
        coords, atom_types, EtaR, ShfR, Zeta, EtaA, out);
}

// Round 5
// 17.504 us; speedup vs baseline: 1.5155x; 1.5155x over previous
//
#include <hip/hip_runtime.h>

namespace {
constexpr int Bc  = 16;
constexpr int Nc  = 96;
constexpr int KRc = 16;
constexpr int KAc = 8;
constexpr int NOUT = KRc + KAc;        // 24
constexpr int NNb  = Nc - 1;           // 95 neighbors per atom
constexpr float RCRf = 5.2f;
constexpr float RCAf = 3.5f;
constexpr float L2E  = 1.4426950408889634f;
}

typedef float v2f __attribute__((ext_vector_type(2)));
typedef float v4f __attribute__((ext_vector_type(4)));

__device__ __forceinline__ v2f sp(float x) { return (v2f){x, x}; }
__device__ __forceinline__ v2f pfma(v2f a, v2f b, v2f c) {
    return __builtin_elementwise_fma(a, b, c);
}
__device__ __forceinline__ v2f pmax(v2f a, v2f b) {
    return __builtin_elementwise_max(a, b);
}
__device__ __forceinline__ v2f pexp2(v2f x) {
    return (v2f){__builtin_amdgcn_exp2f(x.x), __builtin_amdgcn_exp2f(x.y)};
}
__device__ __forceinline__ v2f pcosr(v2f rev) {   // cos(2*pi*rev), rev >= 0
    return (v2f){__builtin_amdgcn_cosf(__builtin_amdgcn_fractf(rev.x)),
                 __builtin_amdgcn_cosf(__builtin_amdgcn_fractf(rev.y))};
}
__device__ __forceinline__ v2f psqrt(v2f x) {
    return (v2f){__builtin_amdgcn_sqrtf(x.x), __builtin_amdgcn_sqrtf(x.y)};
}
__device__ __forceinline__ float cos_rev(float rev) {
    return __builtin_amdgcn_cosf(__builtin_amdgcn_fractf(rev));
}

// 256 threads/block (co-residency: 6 blocks/CU, all 1536 blocks resident).
// Angular: threads t<190 active; j = t%95 fixed per thread (A in registers),
// g = t/95 selects round range (g=0: rr 1..24, g=1: rr 25..47).
// Packed over rr: one v2f iteration covers pairs (j,j+rr) and (j,j+rr+1).
__global__ __launch_bounds__(256, 6) void ani_feat_kernel(
    const float* __restrict__ coords,      // (B,N,3)
    const int*   __restrict__ atom_types,  // (N,)
    const float* __restrict__ EtaR,        // (T,KR)
    const float* __restrict__ ShfR,        // (T,KR)
    const float* __restrict__ Zeta,        // (T,KA)
    const float* __restrict__ EtaA,        // (T,KA)
    float* __restrict__ out)               // (B,N,24)
{
    const int bi = blockIdx.x;             // b*N + i
    const int b  = bi / Nc;
    const int i  = bi - b * Nc;
    const int t  = threadIdx.x;

    __shared__ float ux[96], uy[96], uz[96], ud[96], ufa[96], sfr[96];
    __shared__ v4f  pxy[NNb];              // {x[s],x[s+1],y[s],y[s+1]}
    __shared__ v4f  pzd[NNb];              // {z[s],z[s+1],d[s],d[s+1]}
    __shared__ v2f  pfa[NNb];              // {fa[s],fa[s+1]}
    __shared__ float pr[16][KRc];
    __shared__ float red[4][KAc];

    const int ti = atom_types[i];

    // ---- phase 1: scalar per-neighbor staging (slot 95 mirrors slot 0) ----
    if (t < 96) {
        const float* cb = coords + (size_t)(b * Nc) * 3;
        int s = (t == 95) ? 0 : t;
        int j = s + (s >= i);
        float dx = cb[i*3+0] - cb[j*3+0];
        float dy = cb[i*3+1] - cb[j*3+1];
        float dz = cb[i*3+2] - cb[j*3+2];
        float d2 = dx*dx + dy*dy + dz*dz;
        float d  = __builtin_amdgcn_sqrtf(d2);
        float inv = 1.0f / d;
        ux[t] = dx*inv; uy[t] = dy*inv; uz[t] = dz*inv; ud[t] = d;
        ufa[t] = fmaf(cos_rev(d * (0.5f / RCAf)), 0.5f, 0.5f);
        sfr[t] = fmaf(cos_rev(d * (0.5f / RCRf)), 0.5f, 0.5f);
    }

    // ---- angular parameters + uniform fast-path detection (block-uniform) ----
    float zek[KAc], c1k[KAc], eaL[KAc];
#pragma unroll
    for (int k = 0; k < KAc; ++k) {
        float z = Zeta[ti * KAc + k];
        zek[k] = z;
        c1k[k] = 1.0f - z;
        eaL[k] = EtaA[ti * KAc + k] * L2E;
    }
    bool zuni = true;
#pragma unroll
    for (int k = 1; k < KAc; ++k) zuni = zuni && (zek[k] == zek[0]);
    const float dL = eaL[1] - eaL[0];
    bool arith = true;
#pragma unroll
    for (int k = 2; k < KAc; ++k)
        arith = arith && (fabsf(eaL[k] - (eaL[0] + dL * (float)k)) <=
                          1e-5f * fabsf(eaL[k]) + 1e-7f);
    const bool fast = zuni && arith && (zek[0] == 32.0f);
    const float ea0 = eaL[0], c10 = c1k[0];

    __syncthreads();

    // ---- phase 2: build pair-shifted packed SoA ----
    if (t < NNb) {
        int s1 = t + 1; if (s1 >= NNb) s1 = 0;
        pxy[t] = (v4f){ux[t], ux[s1], uy[t], uy[s1]};
        pzd[t] = (v4f){uz[t], uz[s1], ud[t], ud[s1]};
        pfa[t] = (v2f){ufa[t], ufa[s1]};
    }

    // ---- radial G2 (all 256 threads, from scalar arrays) ----
    {
        const int k = t & 15, g = t >> 4;
        float er  = EtaR[ti * KRc + k];
        float sr  = ShfR[ti * KRc + k];
        float erL = -er * L2E;
        float acc = 0.0f;
        for (int jj = g; jj < NNb; jj += 16) {
            float dd = ud[jj] - sr;
            acc += __builtin_amdgcn_exp2f(erL * dd * dd) * sfr[jj];
        }
        pr[g][k] = acc;
    }
    __syncthreads();

    // ---- angular G3 ----
    const bool act = (t < 2 * NNb);                    // 190 active
    const int  g   = (t >= NNb) ? 1 : 0;
    const int  j   = act ? (t - g * NNb) : 0;
    const float Ax = ux[j], Ay = uy[j], Az = uz[j], Aw = ud[j];
    const float faj  = act ? ufa[j] : 0.0f;
    const float d2A  = Aw * Aw;
    const float m2Aw = -2.0f * Aw;
    const int   rr0  = g ? 25 : 1;

    float av[KAc];
#pragma unroll
    for (int k = 0; k < KAc; ++k) av[k] = 0.0f;

    if (fast) {
        v2f acc2[KAc];
#pragma unroll
        for (int k = 0; k < KAc; ++k) acc2[k] = sp(0.0f);

        if (act) {
            int j2 = j + rr0; if (j2 >= NNb) j2 -= NNb;
            const v2f lastm = g ? (v2f){faj, 0.0f} : (v2f){faj, faj};

#define ANG_BODY(FAJV)                                                      \
            {                                                               \
                v4f xy = pxy[j2];                                           \
                v4f zd = pzd[j2];                                           \
                v2f fb = pfa[j2];                                           \
                v2f Bx = xy.xy, By = xy.zw;                                 \
                v2f Bz = zd.xy, Bw = zd.zw;                                 \
                v2f cosv = pfma(sp(Ax), Bx, pfma(sp(Ay), By, sp(Az)*Bz));   \
                v2f sAB  = pfma(Bw, Bw, sp(d2A));                           \
                v2f d23sq = pmax(pfma(sp(m2Aw)*Bw, cosv, sAB), sp(0.0f));   \
                v2f f23 = pfma(pcosr(psqrt(d23sq) * sp(0.5f/RCAf)),         \
                               sp(0.5f), sp(0.5f));                         \
                v2f fprod = (FAJV) * fb * f23;                              \
                v2f s  = sAB + d23sq;                                       \
                v2f tt = pmax(sp(1.0f) + cosv, sp(0.0f));                   \
                v2f t2 = tt*tt, t4 = t2*t2, t8 = t4*t4, t16 = t8*t8;        \
                v2f F  = t16 * t16 * fprod;                                 \
                v2f e0 = pexp2(pfma(sp(-ea0), s, sp(c10)));                 \
                v2f q  = pexp2(sp(-dL) * s);                                \
                v2f q2 = q * q;                                             \
                v2f e1 = e0*q,  e2 = e0*q2, e3 = e1*q2;                     \
                v2f e4 = e2*q2, e5 = e3*q2, e6 = e4*q2, e7 = e5*q2;         \
                acc2[0] = pfma(F, e0, acc2[0]);                             \
                acc2[1] = pfma(F, e1, acc2[1]);                             \
                acc2[2] = pfma(F, e2, acc2[2]);                             \
                acc2[3] = pfma(F, e3, acc2[3]);                             \
                acc2[4] = pfma(F, e4, acc2[4]);                             \
                acc2[5] = pfma(F, e5, acc2[5]);                             \
                acc2[6] = pfma(F, e6, acc2[6]);                             \
                acc2[7] = pfma(F, e7, acc2[7]);                             \
                j2 += 2; if (j2 >= NNb) j2 -= NNb;                          \
            }

            const v2f fajv = sp(faj);
#pragma unroll 4
            for (int it = 0; it < 11; ++it) {
                ANG_BODY(fajv)
            }
            ANG_BODY(lastm)   // rr = rr0+22 (+23); g==1 masks rr==48
#undef ANG_BODY
        }
#pragma unroll
        for (int k = 0; k < KAc; ++k) av[k] = acc2[k].x + acc2[k].y;
    } else if (act) {
        // generic fallback: scalar per-pair, arbitrary Zeta/EtaA
        float accS[KAc];
#pragma unroll
        for (int k = 0; k < KAc; ++k) accS[k] = 0.0f;
        int j2 = j + rr0; if (j2 >= NNb) j2 -= NNb;
        for (int r = 0; r < 24; ++r) {
            int rr = rr0 + r;
            float lv = (rr <= 47) ? 1.0f : 0.0f;
            float Bx = ux[j2], By = uy[j2], Bz = uz[j2];
            float Bw = ud[j2], fb = ufa[j2];
            float cosv = fmaf(Ax, Bx, fmaf(Ay, By, Az * Bz));
            float sAB  = fmaf(Bw, Bw, d2A);
            float d23sq = fmaxf(fmaf(m2Aw * Bw, cosv, sAB), 0.0f);
            float d23 = __builtin_amdgcn_sqrtf(d23sq);
            float f23 = fmaf(cos_rev(d23 * (0.5f / RCAf)), 0.5f, 0.5f);
            float fprod = faj * fb * f23 * lv;
            float s  = sAB + d23sq;
            float tt = fmaxf(1.0f + cosv, 0.0f);
            float l2 = __builtin_amdgcn_logf(tt);   // log2; -inf at 0 ok
#pragma unroll
            for (int k = 0; k < KAc; ++k) {
                float E = fmaf(zek[k], l2, c1k[k]);
                E = fmaf(-eaL[k], s, E);
                accS[k] += __builtin_amdgcn_exp2f(E) * fprod;
            }
            ++j2; if (j2 >= NNb) j2 = 0;
        }
#pragma unroll
        for (int k = 0; k < KAc; ++k) av[k] = accS[k];
    }

    // ---- reductions ----
    const int lane = t & 63, wv = t >> 6;
#pragma unroll
    for (int k = 0; k < KAc; ++k) {
        float v = av[k];
#pragma unroll
        for (int off = 32; off; off >>= 1) v += __shfl_xor(v, off, 64);
        if (lane == 0) red[wv][k] = v;
    }
    __syncthreads();

    if (t < KAc) {
        out[bi * NOUT + KRc + t] =
            red[0][t] + red[1][t] + red[2][t] + red[3][t];
    }
    if (t < KRc) {
        float s = 0.0f;
#pragma unroll
        for (int g2 = 0; g2 < 16; ++g2) s += pr[g2][t];
        out[bi * NOUT + t] = s;
    }
}

extern "C" void kernel_launch(void* const* d_in, const int* in_sizes, int n_in,
                              void* d_out, int out_size, void* d_ws, size_t ws_size,
                              hipStream_t stream) {
    const float* coords     = (const float*)d_in[0];
    const int*   atom_types = (const int*)d_in[1];
    const float* EtaR       = (const float*)d_in[2];
    const float* ShfR       = (const float*)d_in[3];
    const float* Zeta       = (const float*)d_in[4];
    const float* EtaA       = (const float*)d_in[5];
    float* out = (float*)d_out;

    ani_feat_kernel<<<dim3(Bc * Nc), dim3(256), 0, stream>>>(
        coords, atom_types, EtaR, ShfR, Zeta, EtaA, out);
}